// Round 7
// baseline (383.749 us; speedup 1.0000x reference)
//
#include <hip/hip_runtime.h>
#include <hip/hip_bf16.h>
#include <math.h>

// Problem constants (fixed by the reference)
#define N_NODES   100000
#define N_PAD     100032   // padded row count (multiple of 64) for safe OOB reads
#define N_EDGES   1000000
#define D_IN      64
#define T_ET      4
#define H_DIM     256
#define TD        256      // T_ET * D_IN (mlp fan-in)
#define NSEG      400000   // N_NODES * T_ET

typedef __attribute__((ext_vector_type(8))) short short8;   // 8 bf16 (4 VGPRs)
typedef __attribute__((ext_vector_type(4))) float floatx4;  // MFMA C/D

__device__ __forceinline__ unsigned short f2b(float f) {
    __hip_bfloat16 h = __float2bfloat16(f);
    return *reinterpret_cast<unsigned short*>(&h);
}
__device__ __forceinline__ unsigned pack2(float a, float b) {
    return (unsigned)f2b(a) | ((unsigned)f2b(b) << 16);
}

// ---------------------------------------------------------------------------
// CSR build (unchanged): histogram -> scan -> place
// ---------------------------------------------------------------------------
__global__ __launch_bounds__(256) void hist_kernel(
    const int* __restrict__ edge_index, const int* __restrict__ edge_type,
    int* __restrict__ counts)
{
    int e = blockIdx.x * 256 + threadIdx.x;
    if (e >= N_EDGES) return;
    int dst = edge_index[N_EDGES + e];
    int ty  = edge_type[e];
    atomicAdd(&counts[dst * T_ET + ty], 1);
}

__global__ __launch_bounds__(256) void scan1_kernel(
    const int* __restrict__ counts, int* __restrict__ offsets,
    int* __restrict__ partials)
{
    __shared__ int tsum[256];
    const int tid = threadIdx.x;
    const int base = blockIdx.x * 1024 + tid * 4;
    int v[4]; int s = 0;
    #pragma unroll
    for (int i = 0; i < 4; ++i) {
        v[i] = (base + i < NSEG) ? counts[base + i] : 0;
        s += v[i];
    }
    tsum[tid] = s;
    __syncthreads();
    #pragma unroll
    for (int off = 1; off < 256; off <<= 1) {
        int t = (tid >= off) ? tsum[tid - off] : 0;
        __syncthreads();
        tsum[tid] += t;
        __syncthreads();
    }
    int run = tsum[tid] - s;
    #pragma unroll
    for (int i = 0; i < 4; ++i) {
        if (base + i < NSEG) offsets[base + i] = run;
        run += v[i];
    }
    if (tid == 255) partials[blockIdx.x] = tsum[255];
}

__global__ __launch_bounds__(512) void scan2_kernel(int* __restrict__ partials, int nb)
{
    __shared__ int sh[512];
    const int tid = threadIdx.x;
    int v = (tid < nb) ? partials[tid] : 0;
    sh[tid] = v;
    __syncthreads();
    #pragma unroll
    for (int off = 1; off < 512; off <<= 1) {
        int t = (tid >= off) ? sh[tid - off] : 0;
        __syncthreads();
        sh[tid] += t;
        __syncthreads();
    }
    if (tid < nb) partials[tid] = sh[tid] - v;
}

__global__ __launch_bounds__(256) void scan3_kernel(
    int* __restrict__ offsets, const int* __restrict__ partials,
    int* __restrict__ cursor)
{
    int i = blockIdx.x * 256 + threadIdx.x;
    if (i < NSEG) {
        int o = offsets[i] + partials[i >> 10];
        offsets[i] = o;
        cursor[i]  = o;
    }
    if (i == 0) offsets[NSEG] = N_EDGES;
}

__global__ __launch_bounds__(256) void place_kernel(
    const int* __restrict__ edge_index, const int* __restrict__ edge_type,
    const float* __restrict__ edge_w, int* __restrict__ cursor,
    int2* __restrict__ recs)
{
    int e = blockIdx.x * 256 + threadIdx.x;
    if (e >= N_EDGES) return;
    int src = edge_index[e];
    int dst = edge_index[N_EDGES + e];
    int ty  = edge_type[e];
    int seg = dst * T_ET + ty;
    int pos = atomicAdd(&cursor[seg], 1);
    recs[pos] = make_int2(src, __float_as_int(edge_w[e]));
}

// gather: 16 threads per segment; reads bf16 xb (halves random-read traffic
// vs f32 x), accumulates f32, writes bf16 update.
__global__ __launch_bounds__(256) void gather_kernel(
    const unsigned short* __restrict__ xb, const int* __restrict__ offsets,
    const int2* __restrict__ recs, unsigned* __restrict__ updb_u32)
{
    int gid = blockIdx.x * 256 + threadIdx.x;
    int seg = gid >> 4;
    int t   = gid & 15;
    if (seg >= NSEG) return;
    int start = offsets[seg];
    int end   = offsets[seg + 1];
    float a0 = 0.f, a1 = 0.f, a2 = 0.f, a3 = 0.f;
    for (int p = start; p < end; ++p) {
        int2 r = recs[p];                 // broadcast across the 16 threads
        float w = __int_as_float(r.y);
        uint2 xv = reinterpret_cast<const uint2*>(xb)[r.x * 16 + t];
        a0 += w * __uint_as_float(xv.x << 16);
        a1 += w * __uint_as_float(xv.x & 0xffff0000u);
        a2 += w * __uint_as_float(xv.y << 16);
        a3 += w * __uint_as_float(xv.y & 0xffff0000u);
    }
    uint2 o;
    o.x = pack2(a0, a1);
    o.y = pack2(a2, a3);
    reinterpret_cast<uint2*>(updb_u32)[seg * 16 + t] = o;
}

// ---------------------------------------------------------------------------
// prep: f32 -> bf16 conversions (x padded; w_ih K-permuted to match the
// hidden-LDS pack layout: k(p) = 16*(p>>6) + 64*(p&3) + ((p>>2)&15))
// ---------------------------------------------------------------------------
__global__ __launch_bounds__(256) void conv_x_kernel(
    const float* __restrict__ x, unsigned short* __restrict__ xb)
{
    int i = blockIdx.x * 256 + threadIdx.x;
    if (i >= N_PAD * 16) return;
    int row = i >> 4;
    int srow = row < N_NODES ? row : N_NODES - 1;
    float4 v = reinterpret_cast<const float4*>(x)[srow * 16 + (i & 15)];
    uint2 o;
    o.x = pack2(v.x, v.y);
    o.y = pack2(v.z, v.w);
    reinterpret_cast<uint2*>(xb)[i] = o;
}

__global__ __launch_bounds__(256) void conv_w_kernel(
    const float* __restrict__ w1, const float* __restrict__ wih,
    const float* __restrict__ whh,
    unsigned short* __restrict__ w1b, unsigned short* __restrict__ wihp,
    unsigned short* __restrict__ whhb)
{
    int i = blockIdx.x * 256 + threadIdx.x;
    if (i < 65536) { w1b[i] = f2b(w1[i]); return; }
    i -= 65536;
    if (i < 49152) {
        int n = i >> 8, p = i & 255;
        int k = 16 * (p >> 6) + 64 * (p & 3) + ((p >> 2) & 15);
        wihp[i] = f2b(wih[n * 256 + k]);
        return;
    }
    i -= 49152;
    if (i < 12288) whhb[i] = f2b(whh[i]);
}

// ---------------------------------------------------------------------------
// Staging helpers: fragment-major LDS layout.
// Buffer = 16 fragments x 1024 B. Fragment nf holds B rows nf*16..+15 for one
// 32-wide K step: lane l's 16 B at nf*1024 + l*16 (l = lg*16 + lr).
// Writer thread t owns B row t: chunks c=0..3 at (t>>4)*1024 + c*256 + (t&15)*16
// -> quarter-wave writes/reads are 256 B contiguous: conflict-free.
// ---------------------------------------------------------------------------
__device__ __forceinline__ void stage_issue(
    const unsigned short* __restrict__ src, int strideElems, int kcolElems,
    int nrows, int t, uint4* r)
{
    if (t < nrows) {
        const uint4* s = reinterpret_cast<const uint4*>(
            src + (size_t)t * strideElems + kcolElems);
        r[0] = s[0]; r[1] = s[1]; r[2] = s[2]; r[3] = s[3];
    }
}
__device__ __forceinline__ void stage_write(
    unsigned char* dst, int nrows, int t, const uint4* r)
{
    if (t < nrows) {
        unsigned char* d = dst + (t >> 4) * 1024 + (t & 15) * 16;
        *reinterpret_cast<uint4*>(d)       = r[0];
        *reinterpret_cast<uint4*>(d + 256) = r[1];
        *reinterpret_cast<uint4*>(d + 512) = r[2];
        *reinterpret_cast<uint4*>(d + 768) = r[3];
    }
}

// ---------------------------------------------------------------------------
// Fused MLP + GRU, bf16 MFMA, 64 rows/block, 4 waves (wave = 16 rows, all N).
// v3: double-buffered fragment-major B staging, ONE barrier per K-step;
// global-load latency hides under MFMA of the previous step.
// ---------------------------------------------------------------------------
__global__ __launch_bounds__(256) void fused_mlp_gru_kernel(
    const unsigned short* __restrict__ updb,  // [N_PAD][256] bf16
    const unsigned short* __restrict__ w1b,   // [256][256] bf16
    const float* __restrict__ mlp_b,          // [256]
    const unsigned short* __restrict__ wihp,  // [192][256] bf16, K-permuted
    const unsigned short* __restrict__ whhb,  // [192][64]  bf16
    const float* __restrict__ b_ih,           // [192]
    const float* __restrict__ b_hh,           // [192]
    const float* __restrict__ x,              // [N][64] f32
    const unsigned short* __restrict__ xb,    // [N_PAD][64] bf16
    float* __restrict__ out)                  // [N][64] f32
{
    __shared__ uint4 BsV[2048];               // 32 KB: 2 x 16 KB fragment buffers
    __shared__ uint4 hidV[4][512];            // 32 KB per-wave hidden

    unsigned char* Bs = reinterpret_cast<unsigned char*>(BsV);

    const int tid = threadIdx.x;
    const int w  = tid >> 6;
    const int l  = tid & 63;
    const int lr = l & 15;     // fragment M/N index
    const int lg = l >> 4;     // k-group (0..3)
    const int rowBase = blockIdx.x * 64 + w * 16;

    // ---- A-fragment preloads ----
    short8 af1[8];
    const unsigned short* aRow = updb + (size_t)(rowBase + lr) * 256 + lg * 8;
    #pragma unroll
    for (int kt = 0; kt < 8; ++kt)
        af1[kt] = *reinterpret_cast<const short8*>(aRow + kt * 32);
    short8 af2[2];
    const unsigned short* xRow = xb + (size_t)(rowBase + lr) * 64 + lg * 8;
    af2[0] = *reinterpret_cast<const short8*>(xRow);
    af2[1] = *reinterpret_cast<const short8*>(xRow + 32);

    uint4 rg[4];

    // prologue: stage phase-1 step 0 into buf0
    stage_issue(w1b, 256, 0, 256, tid, rg);
    stage_write(Bs, 256, tid, rg);

    floatx4 acc1[16];
    #pragma unroll
    for (int i = 0; i < 16; ++i) acc1[i] = (floatx4){0.f, 0.f, 0.f, 0.f};

    // ---- phase 1: hidden GEMM, K=256 in 8 steps (1 barrier/step) ----
    #pragma unroll
    for (int kt = 0; kt < 8; ++kt) {
        __syncthreads();
        if (kt < 7) stage_issue(w1b, 256, (kt + 1) * 32, 256, tid, rg);
        else        stage_issue(wihp, 256, 0, 192, tid, rg);
        const unsigned char* bb = Bs + (kt & 1) * 16384;
        #pragma unroll
        for (int nf = 0; nf < 16; ++nf) {
            short8 bf = *reinterpret_cast<const short8*>(bb + nf * 1024 + l * 16);
            acc1[nf] = __builtin_amdgcn_mfma_f32_16x16x32_bf16(af1[kt], bf, acc1[nf], 0, 0, 0);
        }
        stage_write(Bs + ((kt & 1) ^ 1) * 16384, (kt < 7) ? 256 : 192, tid, rg);
    }

    // bias per col (col = nf*16 + lr)
    float b1v[16];
    #pragma unroll
    for (int nf = 0; nf < 16; ++nf) b1v[nf] = mlp_b[nf * 16 + lr];

    // relu + pack to per-wave LDS (K-permuted: p = 64*jj + 4*lr + s,
    // k(p) = 16*jj + 64*s + lr — matched by wihp prep). XOR bank swizzle.
    char* hw = reinterpret_cast<char*>(&hidV[w][0]);
    #pragma unroll
    for (int jj = 0; jj < 4; ++jj) {
        #pragma unroll
        for (int q = 0; q < 4; ++q) {
            int row = lg * 4 + q;
            float v0 = fmaxf(acc1[jj     ][q] + b1v[jj     ], 0.f);
            float v1 = fmaxf(acc1[jj +  4][q] + b1v[jj +  4], 0.f);
            float v2 = fmaxf(acc1[jj +  8][q] + b1v[jj +  8], 0.f);
            float v3 = fmaxf(acc1[jj + 12][q] + b1v[jj + 12], 0.f);
            uint2 pk;
            pk.x = pack2(v0, v1);
            pk.y = pack2(v2, v3);
            int byte = (row * 512 + 128 * jj + 8 * lr) ^ ((row & 7) << 4);
            *reinterpret_cast<uint2*>(hw + byte) = pk;
        }
    }

    floatx4 ai[12], ah[12];
    #pragma unroll
    for (int i = 0; i < 12; ++i) {
        ai[i] = (floatx4){0.f, 0.f, 0.f, 0.f};
        ah[i] = (floatx4){0.f, 0.f, 0.f, 0.f};
    }

    // ---- phase 2a: gi GEMM from wihp, K=256 in 8 steps ----
    // (buffer parity continues: phase-1 kt=7 staged wihp step 0 into buf0)
    #pragma unroll
    for (int kt = 0; kt < 8; ++kt) {
        __syncthreads();
        if (kt < 7) stage_issue(wihp, 256, (kt + 1) * 32, 192, tid, rg);
        else        stage_issue(whhb, 64, 0, 192, tid, rg);
        const unsigned char* bb = Bs + (kt & 1) * 16384;
        int byte = (lr * 512 + kt * 64 + lg * 16) ^ ((lr & 7) << 4);
        short8 af = *reinterpret_cast<const short8*>(hw + byte);
        #pragma unroll
        for (int nf = 0; nf < 12; ++nf) {
            short8 bf = *reinterpret_cast<const short8*>(bb + nf * 1024 + l * 16);
            ai[nf] = __builtin_amdgcn_mfma_f32_16x16x32_bf16(af, bf, ai[nf], 0, 0, 0);
        }
        stage_write(Bs + ((kt & 1) ^ 1) * 16384, 192, tid, rg);
    }

    // ---- phase 2b: gh GEMM from whhb, K=64 in 2 steps ----
    #pragma unroll
    for (int kt = 0; kt < 2; ++kt) {
        __syncthreads();
        if (kt < 1) stage_issue(whhb, 64, 32, 192, tid, rg);
        const unsigned char* bb = Bs + (kt & 1) * 16384;
        #pragma unroll
        for (int nf = 0; nf < 12; ++nf) {
            short8 bf = *reinterpret_cast<const short8*>(bb + nf * 1024 + l * 16);
            ah[nf] = __builtin_amdgcn_mfma_f32_16x16x32_bf16(af2[kt], bf, ah[nf], 0, 0, 0);
        }
        if (kt < 1) stage_write(Bs + 16384, 192, tid, rg);
    }

    // ---- gates + output (thread-local; fast exp) ----
    #pragma unroll
    for (int nf = 0; nf < 4; ++nf) {
        int c = nf * 16 + lr;
        float bir = b_ih[c], biz = b_ih[64 + c], bin = b_ih[128 + c];
        float bhr = b_hh[c], bhz = b_hh[64 + c], bhn = b_hh[128 + c];
        #pragma unroll
        for (int q = 0; q < 4; ++q) {
            int row = rowBase + lg * 4 + q;
            if (row < N_NODES) {
                float ir = ai[nf    ][q] + bir;
                float iz = ai[nf + 4][q] + biz;
                float in_= ai[nf + 8][q] + bin;
                float hr = ah[nf    ][q] + bhr;
                float hz = ah[nf + 4][q] + bhz;
                float hn = ah[nf + 8][q] + bhn;
                float r = 1.0f / (1.0f + __expf(-(ir + hr)));
                float z = 1.0f / (1.0f + __expf(-(iz + hz)));
                float a = in_ + r * hn;
                a = fminf(fmaxf(a, -30.f), 30.f);
                float e2 = __expf(2.0f * a);
                float n = (e2 - 1.0f) / (e2 + 1.0f);
                float xv = x[(size_t)row * 64 + c];
                out[(size_t)row * 64 + c] = (1.0f - z) * n + z * xv;
            }
        }
    }
}

// ---------------------------------------------------------------------------
extern "C" void kernel_launch(void* const* d_in, const int* in_sizes, int n_in,
                              void* d_out, int out_size, void* d_ws, size_t ws_size,
                              hipStream_t stream) {
    const float* node_feature = (const float*)d_in[0];
    const int*   edge_index   = (const int*)d_in[1];
    const int*   edge_type    = (const int*)d_in[2];
    const float* edge_weight  = (const float*)d_in[3];
    const float* mlp_W        = (const float*)d_in[4];
    const float* mlp_b        = (const float*)d_in[5];
    const float* w_ih         = (const float*)d_in[6];
    const float* w_hh         = (const float*)d_in[7];
    const float* b_ih         = (const float*)d_in[8];
    const float* b_hh         = (const float*)d_in[9];
    float* out = (float*)d_out;

    // workspace layout (bf16 regions first, then CSR ints)
    unsigned short* updb = (unsigned short*)d_ws;          // [N_PAD][256]
    unsigned short* xb   = updb + (size_t)N_PAD * 256;     // [N_PAD][64]
    unsigned short* w1b  = xb   + (size_t)N_PAD * 64;      // [256][256]
    unsigned short* wihp = w1b  + 65536;                   // [192][256]
    unsigned short* whhb = wihp + 49152;                   // [192][64]
    int* counts   = (int*)(whhb + 12288);                  // [NSEG]
    int* offsets  = counts + 400064;                       // [NSEG+1]
    int* partials = offsets + 400064;                      // [512]
    int* cursor   = partials + 512;                        // [NSEG]
    int2* recs    = (int2*)(cursor + 400064);              // [E]

    const int NB1 = (NSEG + 1023) / 1024;

    hipMemsetAsync(counts, 0, (size_t)NSEG * sizeof(int), stream);

    conv_x_kernel<<<(N_PAD * 16 + 255) / 256, 256, 0, stream>>>(node_feature, xb);
    conv_w_kernel<<<(126976 + 255) / 256, 256, 0, stream>>>(
        mlp_W, w_ih, w_hh, w1b, wihp, whhb);

    hist_kernel<<<(N_EDGES + 255) / 256, 256, 0, stream>>>(
        edge_index, edge_type, counts);
    scan1_kernel<<<NB1, 256, 0, stream>>>(counts, offsets, partials);
    scan2_kernel<<<1, 512, 0, stream>>>(partials, NB1);
    scan3_kernel<<<(NSEG + 255) / 256, 256, 0, stream>>>(offsets, partials, cursor);
    place_kernel<<<(N_EDGES + 255) / 256, 256, 0, stream>>>(
        edge_index, edge_type, edge_weight, cursor, recs);
    gather_kernel<<<(NSEG * 16 + 255) / 256, 256, 0, stream>>>(
        xb, offsets, recs, (unsigned*)updb);

    fused_mlp_gru_kernel<<<(N_NODES + 63) / 64, 256, 0, stream>>>(
        updb, w1b, mlp_b, wihp, whhb, b_ih, b_hh, node_feature, xb, out);
}

// Round 8
// 368.958 us; speedup vs baseline: 1.0401x; 1.0401x over previous
//
#include <hip/hip_runtime.h>
#include <hip/hip_bf16.h>
#include <math.h>

// Problem constants (fixed by the reference)
#define N_NODES   100000
#define N_PAD     100032   // padded row count (multiple of 64) for safe OOB reads
#define N_EDGES   1000000
#define D_IN      64
#define T_ET      4
#define H_DIM     256
#define TD        256      // T_ET * D_IN (mlp fan-in)
#define NSEG      400000   // N_NODES * T_ET

typedef __attribute__((ext_vector_type(8))) short short8;   // 8 bf16 (4 VGPRs)
typedef __attribute__((ext_vector_type(4))) float floatx4;  // MFMA C/D

__device__ __forceinline__ unsigned short f2b(float f) {
    __hip_bfloat16 h = __float2bfloat16(f);
    return *reinterpret_cast<unsigned short*>(&h);
}
__device__ __forceinline__ unsigned pack2(float a, float b) {
    return (unsigned)f2b(a) | ((unsigned)f2b(b) << 16);
}

// global->LDS DMA: 16 B per lane, LDS dst = wave-uniform base + lane*16
#define GLOAD16(gsrc, ldst)                                                  \
    __builtin_amdgcn_global_load_lds(                                        \
        (const __attribute__((address_space(1))) unsigned int*)(gsrc),       \
        (__attribute__((address_space(3))) unsigned int*)(ldst), 16, 0, 0)

// ---------------------------------------------------------------------------
// CSR build (unchanged): histogram -> scan -> place
// ---------------------------------------------------------------------------
__global__ __launch_bounds__(256) void hist_kernel(
    const int* __restrict__ edge_index, const int* __restrict__ edge_type,
    int* __restrict__ counts)
{
    int e = blockIdx.x * 256 + threadIdx.x;
    if (e >= N_EDGES) return;
    int dst = edge_index[N_EDGES + e];
    int ty  = edge_type[e];
    atomicAdd(&counts[dst * T_ET + ty], 1);
}

__global__ __launch_bounds__(256) void scan1_kernel(
    const int* __restrict__ counts, int* __restrict__ offsets,
    int* __restrict__ partials)
{
    __shared__ int tsum[256];
    const int tid = threadIdx.x;
    const int base = blockIdx.x * 1024 + tid * 4;
    int v[4]; int s = 0;
    #pragma unroll
    for (int i = 0; i < 4; ++i) {
        v[i] = (base + i < NSEG) ? counts[base + i] : 0;
        s += v[i];
    }
    tsum[tid] = s;
    __syncthreads();
    #pragma unroll
    for (int off = 1; off < 256; off <<= 1) {
        int t = (tid >= off) ? tsum[tid - off] : 0;
        __syncthreads();
        tsum[tid] += t;
        __syncthreads();
    }
    int run = tsum[tid] - s;
    #pragma unroll
    for (int i = 0; i < 4; ++i) {
        if (base + i < NSEG) offsets[base + i] = run;
        run += v[i];
    }
    if (tid == 255) partials[blockIdx.x] = tsum[255];
}

__global__ __launch_bounds__(512) void scan2_kernel(int* __restrict__ partials, int nb)
{
    __shared__ int sh[512];
    const int tid = threadIdx.x;
    int v = (tid < nb) ? partials[tid] : 0;
    sh[tid] = v;
    __syncthreads();
    #pragma unroll
    for (int off = 1; off < 512; off <<= 1) {
        int t = (tid >= off) ? sh[tid - off] : 0;
        __syncthreads();
        sh[tid] += t;
        __syncthreads();
    }
    if (tid < nb) partials[tid] = sh[tid] - v;
}

__global__ __launch_bounds__(256) void scan3_kernel(
    int* __restrict__ offsets, const int* __restrict__ partials,
    int* __restrict__ cursor)
{
    int i = blockIdx.x * 256 + threadIdx.x;
    if (i < NSEG) {
        int o = offsets[i] + partials[i >> 10];
        offsets[i] = o;
        cursor[i]  = o;
    }
    if (i == 0) offsets[NSEG] = N_EDGES;
}

__global__ __launch_bounds__(256) void place_kernel(
    const int* __restrict__ edge_index, const int* __restrict__ edge_type,
    const float* __restrict__ edge_w, int* __restrict__ cursor,
    int2* __restrict__ recs)
{
    int e = blockIdx.x * 256 + threadIdx.x;
    if (e >= N_EDGES) return;
    int src = edge_index[e];
    int dst = edge_index[N_EDGES + e];
    int ty  = edge_type[e];
    int seg = dst * T_ET + ty;
    int pos = atomicAdd(&cursor[seg], 1);
    recs[pos] = make_int2(src, __float_as_int(edge_w[e]));
}

// gather: 16 threads per segment; reads bf16 xb, accumulates f32, writes bf16
__global__ __launch_bounds__(256) void gather_kernel(
    const unsigned short* __restrict__ xb, const int* __restrict__ offsets,
    const int2* __restrict__ recs, unsigned* __restrict__ updb_u32)
{
    int gid = blockIdx.x * 256 + threadIdx.x;
    int seg = gid >> 4;
    int t   = gid & 15;
    if (seg >= NSEG) return;
    int start = offsets[seg];
    int end   = offsets[seg + 1];
    float a0 = 0.f, a1 = 0.f, a2 = 0.f, a3 = 0.f;
    for (int p = start; p < end; ++p) {
        int2 r = recs[p];                 // broadcast across the 16 threads
        float w = __int_as_float(r.y);
        uint2 xv = reinterpret_cast<const uint2*>(xb)[r.x * 16 + t];
        a0 += w * __uint_as_float(xv.x << 16);
        a1 += w * __uint_as_float(xv.x & 0xffff0000u);
        a2 += w * __uint_as_float(xv.y << 16);
        a3 += w * __uint_as_float(xv.y & 0xffff0000u);
    }
    uint2 o;
    o.x = pack2(a0, a1);
    o.y = pack2(a2, a3);
    reinterpret_cast<uint2*>(updb_u32)[seg * 16 + t] = o;
}

// ---------------------------------------------------------------------------
// prep: f32 -> bf16. w_ih K-permuted with the NEW pack layout:
//   physical p -> logical k:  k(p) = (p>>6)*64 + (p&3)*16 + ((p>>2)&15)
// (phase-1 wave w packs its 64-col block b=w as p_local = lr*4 + cf',
//  logical col c_local = cf'*16 + lr — verified element-wise.)
// ---------------------------------------------------------------------------
__global__ __launch_bounds__(256) void conv_x_kernel(
    const float* __restrict__ x, unsigned short* __restrict__ xb)
{
    int i = blockIdx.x * 256 + threadIdx.x;
    if (i >= N_PAD * 16) return;
    int row = i >> 4;
    int srow = row < N_NODES ? row : N_NODES - 1;
    float4 v = reinterpret_cast<const float4*>(x)[srow * 16 + (i & 15)];
    uint2 o;
    o.x = pack2(v.x, v.y);
    o.y = pack2(v.z, v.w);
    reinterpret_cast<uint2*>(xb)[i] = o;
}

__global__ __launch_bounds__(256) void conv_w_kernel(
    const float* __restrict__ w1, const float* __restrict__ wih,
    const float* __restrict__ whh,
    unsigned short* __restrict__ w1b, unsigned short* __restrict__ wihp,
    unsigned short* __restrict__ whhb)
{
    int i = blockIdx.x * 256 + threadIdx.x;
    if (i < 65536) { w1b[i] = f2b(w1[i]); return; }
    i -= 65536;
    if (i < 49152) {
        int n = i >> 8, p = i & 255;
        int k = (p >> 6) * 64 + (p & 3) * 16 + ((p >> 2) & 15);
        wihp[i] = f2b(wih[n * 256 + k]);
        return;
    }
    i -= 49152;
    if (i < 12288) whhb[i] = f2b(whh[i]);
}

// ---------------------------------------------------------------------------
// Fused MLP + GRU, bf16 MFMA 16x16x32, 64 rows/block, 4 waves, N-SPLIT:
//   phase 1: wave w owns cols w*64..+63 (frags w*4..w*4+3), all 64 rows.
//   phase 2: wave w owns gi/gh frags {w, w+4, w+8} (col w*16+lr per gate)
//            -> matched (r,z,n) triplets stay thread-local.
// B staged via global_load_lds (conflict-free contiguous DMA), double-buffered,
// one barrier per K-step (m97 structure). A per-lane from global (L1-hot).
// hid handoff: [64][256] bf16 in LDS, XOR-swizzled, K-permuted (see conv_w).
// LDS: 2x16KB Bs + 32KB hid = 64 KB -> 2 blocks/CU.
// ---------------------------------------------------------------------------
__global__ __launch_bounds__(256) void fused_mlp_gru_kernel(
    const unsigned short* __restrict__ updb,  // [N_PAD][256] bf16
    const unsigned short* __restrict__ w1b,   // [256][256] bf16
    const float* __restrict__ mlp_b,          // [256]
    const unsigned short* __restrict__ wihp,  // [192][256] bf16, K-permuted
    const unsigned short* __restrict__ whhb,  // [192][64]  bf16
    const float* __restrict__ b_ih,           // [192]
    const float* __restrict__ b_hh,           // [192]
    const float* __restrict__ x,              // [N][64] f32
    const unsigned short* __restrict__ xb,    // [N_PAD][64] bf16
    float* __restrict__ out)                  // [N][64] f32
{
    __shared__ __align__(16) char lds[65536]; // [0,16K) buf0 | [16K,32K) buf1 | [32K,64K) hid
    char* hid = lds + 32768;

    const int tid = threadIdx.x;
    const int w  = tid >> 6;
    const int l  = tid & 63;
    const int lr = l & 15;     // fragment row/col index
    const int lg = l >> 4;     // k-chunk (0..3)
    const int rowBase = blockIdx.x * 64;

    // ---- prologue: stage phase-1 step 0 into buf0 (4 DMA per wave) ----
    #pragma unroll
    for (int f = 0; f < 4; ++f) {
        int nf = w * 4 + f;
        GLOAD16(w1b + (size_t)(nf * 16 + lr) * 256 + lg * 8, lds + nf * 1024);
    }
    __syncthreads();

    floatx4 acc1[16];   // [rf*4+cf]: rows rf*16+lg*4+q, col w*64+cf*16+lr
    #pragma unroll
    for (int i = 0; i < 16; ++i) acc1[i] = (floatx4){0.f, 0.f, 0.f, 0.f};

    // ---- phase 1: hidden GEMM, K=256, 8 steps, 1 barrier/step ----
    #pragma unroll
    for (int kt = 0; kt < 8; ++kt) {
        const int cur = kt & 1;
        // issue next-step DMA (hides under this step's loads+MFMA)
        if (kt < 7) {
            #pragma unroll
            for (int f = 0; f < 4; ++f) {
                int nf = w * 4 + f;
                GLOAD16(w1b + (size_t)(nf * 16 + lr) * 256 + (kt + 1) * 32 + lg * 8,
                        lds + (cur ^ 1) * 16384 + nf * 1024);
            }
        } else {
            #pragma unroll
            for (int f = 0; f < 3; ++f) {
                int nf = w + f * 4;
                GLOAD16(wihp + (size_t)(nf * 16 + lr) * 256 + lg * 8,
                        lds + (cur ^ 1) * 16384 + nf * 1024);
            }
        }
        // A fragments per-lane from global (64B-coalesced, L1-hot)
        short8 af[4];
        #pragma unroll
        for (int rf = 0; rf < 4; ++rf)
            af[rf] = *reinterpret_cast<const short8*>(
                updb + (size_t)(rowBase + rf * 16 + lr) * 256 + kt * 32 + lg * 8);
        // B fragments: wave reads ONLY its 4 frags (contiguous 1KB each)
        #pragma unroll
        for (int f = 0; f < 4; ++f) {
            short8 bf = *reinterpret_cast<const short8*>(
                lds + cur * 16384 + (w * 4 + f) * 1024 + l * 16);
            #pragma unroll
            for (int rf = 0; rf < 4; ++rf)
                acc1[rf * 4 + f] =
                    __builtin_amdgcn_mfma_f32_16x16x32_bf16(af[rf], bf, acc1[rf * 4 + f], 0, 0, 0);
        }
        __syncthreads();
    }

    // ---- pack hidden -> LDS (relu + bias), XOR swizzle ----
    // wave w, cols w*64 + cf*16 + lr; pk holds cf=0..3 -> p_local = lr*4+cf
    float b1v[4];
    #pragma unroll
    for (int cf = 0; cf < 4; ++cf) b1v[cf] = mlp_b[w * 64 + cf * 16 + lr];
    #pragma unroll
    for (int rf = 0; rf < 4; ++rf) {
        #pragma unroll
        for (int q = 0; q < 4; ++q) {
            int row = rf * 16 + lg * 4 + q;
            float v0 = fmaxf(acc1[rf * 4 + 0][q] + b1v[0], 0.f);
            float v1 = fmaxf(acc1[rf * 4 + 1][q] + b1v[1], 0.f);
            float v2 = fmaxf(acc1[rf * 4 + 2][q] + b1v[2], 0.f);
            float v3 = fmaxf(acc1[rf * 4 + 3][q] + b1v[3], 0.f);
            uint2 pk;
            pk.x = pack2(v0, v1);
            pk.y = pack2(v2, v3);
            int byte = (row * 512 + w * 128 + lr * 8) ^ ((row & 7) << 4);
            *reinterpret_cast<uint2*>(hid + byte) = pk;
        }
    }

    // preload phase-2b A fragments (xb rows)
    short8 afx[4][2];
    #pragma unroll
    for (int rf = 0; rf < 4; ++rf) {
        #pragma unroll
        for (int kt = 0; kt < 2; ++kt)
            afx[rf][kt] = *reinterpret_cast<const short8*>(
                xb + (size_t)(rowBase + rf * 16 + lr) * 64 + kt * 32 + lg * 8);
    }

    __syncthreads();   // hid visible to all waves; buf0 (wihp step 0) drained

    floatx4 ai[12], ah[12];   // [rf*3+f]: gate f, col w*16+lr, rows rf*16+lg*4+q
    #pragma unroll
    for (int i = 0; i < 12; ++i) {
        ai[i] = (floatx4){0.f, 0.f, 0.f, 0.f};
        ah[i] = (floatx4){0.f, 0.f, 0.f, 0.f};
    }

    // ---- phase 2a: gi GEMM (K=256 physical, 8 steps) ----
    #pragma unroll
    for (int kt = 0; kt < 8; ++kt) {
        const int cur = kt & 1;
        if (kt < 7) {
            #pragma unroll
            for (int f = 0; f < 3; ++f) {
                int nf = w + f * 4;
                GLOAD16(wihp + (size_t)(nf * 16 + lr) * 256 + (kt + 1) * 32 + lg * 8,
                        lds + (cur ^ 1) * 16384 + nf * 1024);
            }
        } else {
            #pragma unroll
            for (int f = 0; f < 3; ++f) {
                int nf = w + f * 4;
                GLOAD16(whhb + (size_t)(nf * 16 + lr) * 64 + lg * 8,
                        lds + (cur ^ 1) * 16384 + nf * 1024);
            }
        }
        // A from hid (swizzled; 2-way-uniform banks)
        short8 af[4];
        #pragma unroll
        for (int rf = 0; rf < 4; ++rf) {
            int row = rf * 16 + lr;
            int byte = (row * 512 + kt * 64 + lg * 16) ^ ((row & 7) << 4);
            af[rf] = *reinterpret_cast<const short8*>(hid + byte);
        }
        #pragma unroll
        for (int f = 0; f < 3; ++f) {
            short8 bf = *reinterpret_cast<const short8*>(
                lds + cur * 16384 + (w + f * 4) * 1024 + l * 16);
            #pragma unroll
            for (int rf = 0; rf < 4; ++rf)
                ai[rf * 3 + f] =
                    __builtin_amdgcn_mfma_f32_16x16x32_bf16(af[rf], bf, ai[rf * 3 + f], 0, 0, 0);
        }
        __syncthreads();
    }

    // ---- phase 2b: gh GEMM (K=64, 2 steps) ----
    #pragma unroll
    for (int kt = 0; kt < 2; ++kt) {
        const int cur = kt & 1;
        if (kt < 1) {
            #pragma unroll
            for (int f = 0; f < 3; ++f) {
                int nf = w + f * 4;
                GLOAD16(whhb + (size_t)(nf * 16 + lr) * 64 + 32 + lg * 8,
                        lds + (cur ^ 1) * 16384 + nf * 1024);
            }
        }
        #pragma unroll
        for (int f = 0; f < 3; ++f) {
            short8 bf = *reinterpret_cast<const short8*>(
                lds + cur * 16384 + (w + f * 4) * 1024 + l * 16);
            #pragma unroll
            for (int rf = 0; rf < 4; ++rf)
                ah[rf * 3 + f] =
                    __builtin_amdgcn_mfma_f32_16x16x32_bf16(afx[rf][kt], bf, ah[rf * 3 + f], 0, 0, 0);
        }
        __syncthreads();
    }

    // ---- gates + output: col c = w*16 + lr (per gate), thread-local ----
    const int c = w * 16 + lr;
    const float bir = b_ih[c],       bhr = b_hh[c];
    const float biz = b_ih[64 + c],  bhz = b_hh[64 + c];
    const float bin = b_ih[128 + c], bhn = b_hh[128 + c];
    #pragma unroll
    for (int rf = 0; rf < 4; ++rf) {
        #pragma unroll
        for (int q = 0; q < 4; ++q) {
            int row = rowBase + rf * 16 + lg * 4 + q;
            if (row < N_NODES) {
                float ir = ai[rf * 3 + 0][q] + bir;
                float iz = ai[rf * 3 + 1][q] + biz;
                float in_= ai[rf * 3 + 2][q] + bin;
                float hr = ah[rf * 3 + 0][q] + bhr;
                float hz = ah[rf * 3 + 1][q] + bhz;
                float hn = ah[rf * 3 + 2][q] + bhn;
                float r = 1.0f / (1.0f + __expf(-(ir + hr)));
                float z = 1.0f / (1.0f + __expf(-(iz + hz)));
                float a = in_ + r * hn;
                a = fminf(fmaxf(a, -30.f), 30.f);
                float e2 = __expf(2.0f * a);
                float n = (e2 - 1.0f) / (e2 + 1.0f);
                float xv = x[(size_t)row * 64 + c];
                out[(size_t)row * 64 + c] = (1.0f - z) * n + z * xv;
            }
        }
    }
}

// ---------------------------------------------------------------------------
extern "C" void kernel_launch(void* const* d_in, const int* in_sizes, int n_in,
                              void* d_out, int out_size, void* d_ws, size_t ws_size,
                              hipStream_t stream) {
    const float* node_feature = (const float*)d_in[0];
    const int*   edge_index   = (const int*)d_in[1];
    const int*   edge_type    = (const int*)d_in[2];
    const float* edge_weight  = (const float*)d_in[3];
    const float* mlp_W        = (const float*)d_in[4];
    const float* mlp_b        = (const float*)d_in[5];
    const float* w_ih         = (const float*)d_in[6];
    const float* w_hh         = (const float*)d_in[7];
    const float* b_ih         = (const float*)d_in[8];
    const float* b_hh         = (const float*)d_in[9];
    float* out = (float*)d_out;

    // workspace layout (bf16 regions first, then CSR ints)
    unsigned short* updb = (unsigned short*)d_ws;          // [N_PAD][256]
    unsigned short* xb   = updb + (size_t)N_PAD * 256;     // [N_PAD][64]
    unsigned short* w1b  = xb   + (size_t)N_PAD * 64;      // [256][256]
    unsigned short* wihp = w1b  + 65536;                   // [192][256]
    unsigned short* whhb = wihp + 49152;                   // [192][64]
    int* counts   = (int*)(whhb + 12288);                  // [NSEG]
    int* offsets  = counts + 400064;                       // [NSEG+1]
    int* partials = offsets + 400064;                      // [512]
    int* cursor   = partials + 512;                        // [NSEG]
    int2* recs    = (int2*)(cursor + 400064);              // [E]

    const int NB1 = (NSEG + 1023) / 1024;

    hipMemsetAsync(counts, 0, (size_t)NSEG * sizeof(int), stream);

    conv_x_kernel<<<(N_PAD * 16 + 255) / 256, 256, 0, stream>>>(node_feature, xb);
    conv_w_kernel<<<(126976 + 255) / 256, 256, 0, stream>>>(
        mlp_W, w_ih, w_hh, w1b, wihp, whhb);

    hist_kernel<<<(N_EDGES + 255) / 256, 256, 0, stream>>>(
        edge_index, edge_type, counts);
    scan1_kernel<<<NB1, 256, 0, stream>>>(counts, offsets, partials);
    scan2_kernel<<<1, 512, 0, stream>>>(partials, NB1);
    scan3_kernel<<<(NSEG + 255) / 256, 256, 0, stream>>>(offsets, partials, cursor);
    place_kernel<<<(N_EDGES + 255) / 256, 256, 0, stream>>>(
        edge_index, edge_type, edge_weight, cursor, recs);
    gather_kernel<<<(NSEG * 16 + 255) / 256, 256, 0, stream>>>(
        xb, offsets, recs, (unsigned*)updb);

    fused_mlp_gru_kernel<<<(N_NODES + 63) / 64, 256, 0, stream>>>(
        updb, w1b, mlp_b, wihp, whhb, b_ih, b_hh, node_feature, xb, out);
}